// Round 1
// baseline (410.793 us; speedup 1.0000x reference)
//
#include <hip/hip_runtime.h>
#include <math.h>

#define NUM_CLASSES 81
#define BATCH 64
#define P 8732
#define M 24
#define THRESH 0.5f

__device__ __forceinline__ float sl1(float d) {
    float a = fabsf(d);
    return a < 1.f ? 0.5f * a * a : a - 0.5f;
}

// ---------------- Kernel 1: matching + loc loss (one block per batch) ----------------
__global__ __launch_bounds__(256) void match_kernel(
    const float* __restrict__ loc_data,   // [B,P,4]
    const float* __restrict__ priors,     // [P,4] center-size
    const float* __restrict__ truths,     // [B,M,4] corners
    const int*   __restrict__ labels,     // [B,M]
    int*    __restrict__ conf_t,          // [B,P] out
    int*    __restrict__ num_pos,         // [B] out
    double* __restrict__ loss_l_out)      // [B] out
{
    const int b   = blockIdx.x;
    const int tid = threadIdx.x;

    __shared__ float s_truth[M][4];
    __shared__ float s_area[M];
    __shared__ int   s_label[M];
    __shared__ float s_bto[P];            // best_truth_overlap per prior (35KB)
    __shared__ unsigned char s_bti[P];    // best_truth_idx per prior
    __shared__ float s_wbest[4][M];
    __shared__ int   s_wbidx[4][M];
    __shared__ int   s_bpi[M];
    __shared__ double s_dl[4];
    __shared__ int    s_np[4];

    if (tid < M * 4) ((float*)s_truth)[tid] = truths[b * M * 4 + tid];
    if (tid < M)     s_label[tid] = labels[b * M + tid];
    __syncthreads();
    if (tid < M)
        s_area[tid] = (s_truth[tid][2] - s_truth[tid][0]) * (s_truth[tid][3] - s_truth[tid][1]);
    __syncthreads();

    // per-thread per-truth best (over this thread's priors)
    float tb_val[M];
    int   tb_idx[M];
#pragma unroll
    for (int m = 0; m < M; ++m) { tb_val[m] = -1.0f; tb_idx[m] = 0; }

    for (int p = tid; p < P; p += 256) {
        float4 pr = ((const float4*)priors)[p];
        float bx0 = pr.x - pr.z * 0.5f, by0 = pr.y - pr.w * 0.5f;
        float bx1 = pr.x + pr.z * 0.5f, by1 = pr.y + pr.w * 0.5f;
        float area_b = (bx1 - bx0) * (by1 - by0);
        float best = -1.f; int besti = 0;
#pragma unroll
        for (int m = 0; m < M; ++m) {
            float lx = fmaxf(s_truth[m][0], bx0);
            float ly = fmaxf(s_truth[m][1], by0);
            float rx = fminf(s_truth[m][2], bx1);
            float ry = fminf(s_truth[m][3], by1);
            float w = fmaxf(rx - lx, 0.f), h = fmaxf(ry - ly, 0.f);
            float inter = w * h;
            float iou = inter / (s_area[m] + area_b - inter);
            if (iou > best) { best = iou; besti = m; }          // first m wins
            if (iou > tb_val[m]) { tb_val[m] = iou; tb_idx[m] = p; }  // smallest p wins
        }
        s_bto[p] = best;
        s_bti[p] = (unsigned char)besti;
    }

    // wave-level reduce of per-truth best (prefer larger val, tie -> smaller idx)
#pragma unroll
    for (int m = 0; m < M; ++m) {
        float v = tb_val[m]; int ix = tb_idx[m];
        for (int off = 32; off; off >>= 1) {
            float vo = __shfl_xor(v, off);
            int   io = __shfl_xor(ix, off);
            if (vo > v || (vo == v && io < ix)) { v = vo; ix = io; }
        }
        tb_val[m] = v; tb_idx[m] = ix;
    }
    const int wid = tid >> 6;
    if ((tid & 63) == 0) {
#pragma unroll
        for (int m = 0; m < M; ++m) { s_wbest[wid][m] = tb_val[m]; s_wbidx[wid][m] = tb_idx[m]; }
    }
    __syncthreads();
    if (tid < M) {
        float v = s_wbest[0][tid]; int ix = s_wbidx[0][tid];
        for (int w = 1; w < 4; ++w) {
            float vo = s_wbest[w][tid]; int io = s_wbidx[w][tid];
            if (vo > v || (vo == v && io < ix)) { v = vo; ix = io; }
        }
        s_bpi[tid] = ix;
    }
    __syncthreads();
    // forced matches: sequential, last m wins on collision (numpy scatter semantics)
    if (tid == 0) {
        for (int m = 0; m < M; ++m) {
            int p = s_bpi[m];
            s_bto[p] = 2.0f;
            s_bti[p] = (unsigned char)m;
        }
    }
    __syncthreads();

    // phase B: conf_t, encode, smooth-L1
    double lsum = 0.0;
    int npos = 0;
    for (int p = tid; p < P; p += 256) {
        float ov = s_bto[p];
        int m = (int)s_bti[p];
        int conf = (ov < THRESH) ? 0 : (s_label[m] + 1);
        conf_t[(size_t)b * P + p] = conf;
        if (conf > 0) {
            ++npos;
            float4 pr = ((const float4*)priors)[p];
            float x0 = s_truth[m][0], y0 = s_truth[m][1];
            float x1 = s_truth[m][2], y1 = s_truth[m][3];
            float gcx = ((x0 + x1) * 0.5f - pr.x) / (0.1f * pr.z);
            float gcy = ((y0 + y1) * 0.5f - pr.y) / (0.1f * pr.w);
            float gw  = logf((x1 - x0) / pr.z) / 0.2f;
            float gh  = logf((y1 - y0) / pr.w) / 0.2f;
            float4 ld = ((const float4*)loc_data)[(size_t)b * P + p];
            float s = sl1(ld.x - gcx) + sl1(ld.y - gcy) + sl1(ld.z - gw) + sl1(ld.w - gh);
            lsum += (double)s;
        }
    }
    for (int off = 32; off; off >>= 1) {
        lsum += __shfl_xor(lsum, off);
        npos += __shfl_xor(npos, off);
    }
    if ((tid & 63) == 0) { s_dl[wid] = lsum; s_np[wid] = npos; }
    __syncthreads();
    if (tid == 0) {
        loss_l_out[b] = s_dl[0] + s_dl[1] + s_dl[2] + s_dl[3];
        num_pos[b]    = s_np[0] + s_np[1] + s_np[2] + s_np[3];
    }
}

// ---------------- Kernel 2: cross-entropy per prior (one wave per row) ----------------
__global__ __launch_bounds__(256) void ce_kernel(
    const float* __restrict__ conf_data,  // [B,P,C]
    int*         __restrict__ conf_t,     // [B,P] read as int, overwritten as float loss_rank
    double*      __restrict__ pos_ce)     // [B] accumulators (pre-zeroed)
{
    const int lane = threadIdx.x & 63;
    const int wid  = threadIdx.x >> 6;
    const int wpb  = blockDim.x >> 6;
    const int nw   = wpb * gridDim.x;
    const int R    = BATCH * P;

    for (int r = blockIdx.x * wpb + wid; r < R; r += nw) {
        const float* x = conf_data + (size_t)r * NUM_CLASSES;
        float a = x[lane];
        float c2 = (lane < NUM_CLASSES - 64) ? x[64 + lane] : -INFINITY;
        float mx = fmaxf(a, c2);
        for (int off = 32; off; off >>= 1) mx = fmaxf(mx, __shfl_xor(mx, off));
        float se = expf(a - mx) + ((lane < NUM_CLASSES - 64) ? expf(c2 - mx) : 0.f);
        for (int off = 32; off; off >>= 1) se += __shfl_xor(se, off);
        int ct = conf_t[r];
        float picked = x[ct];
        float ce = mx + logf(se) - picked;
        if (lane == 0) {
            if (ct > 0) {
                ((float*)conf_t)[r] = 0.0f;                   // positives ranked 0
                atomicAdd(&pos_ce[r / P], (double)ce);
            } else {
                ((float*)conf_t)[r] = ce;                     // nonneg
            }
        }
    }
}

// ---------------- Kernel 3: top-k sum via radix select (one block per batch) ----------------
__global__ __launch_bounds__(256) void topk_kernel(
    const float*  __restrict__ loss_rank, // [B,P] nonneg floats
    const int*    __restrict__ num_pos,   // [B]
    const double* __restrict__ pos_ce,    // [B]
    double*       __restrict__ loss_c)    // [B] out
{
    const int b   = blockIdx.x;
    const int tid = threadIdx.x;
    __shared__ unsigned int s_key[P];
    __shared__ unsigned int s_hist[256];
    __shared__ unsigned int s_prefix;
    __shared__ int s_rem;
    __shared__ double s_dl[4];
    __shared__ int    s_ci[4];

    const unsigned int* src = (const unsigned int*)(loss_rank + (size_t)b * P);
    for (int p = tid; p < P; p += 256) s_key[p] = src[p];
    int k = num_pos[b] * 3;
    if (k > P - 1) k = P - 1;
    __syncthreads();

    unsigned int prefix = 0;
    if (k > 0) {
        int rem = k;
        for (int byte = 3; byte >= 0; --byte) {
            if (tid < 256) s_hist[tid] = 0;
            __syncthreads();
            unsigned int himask = (byte == 3) ? 0u : (0xFFFFFFFFu << ((byte + 1) * 8));
            for (int p = tid; p < P; p += 256) {
                unsigned int key = s_key[p];
                if ((key & himask) == prefix)
                    atomicAdd(&s_hist[(key >> (byte * 8)) & 255u], 1u);
            }
            __syncthreads();
            if (tid == 0) {
                int cum = 0, chosen = 0;
                for (int bk = 255; bk >= 0; --bk) {
                    int c = (int)s_hist[bk];
                    if (cum + c >= rem) { chosen = bk; break; }
                    cum += c;
                }
                s_prefix = prefix | ((unsigned)chosen << (byte * 8));
                s_rem = rem - cum;
            }
            __syncthreads();
            prefix = rem ? s_prefix : s_prefix;  // all threads read
            prefix = s_prefix;
            rem    = s_rem;
        }
    }

    // sum of values strictly greater than T, plus (k - cnt) copies of T
    double sum_gt = 0.0;
    int    cnt_gt = 0;
    if (k > 0) {
        for (int p = tid; p < P; p += 256) {
            unsigned int key = s_key[p];
            if (key > prefix) { sum_gt += (double)__uint_as_float(key); ++cnt_gt; }
        }
    }
    for (int off = 32; off; off >>= 1) {
        sum_gt += __shfl_xor(sum_gt, off);
        cnt_gt += __shfl_xor(cnt_gt, off);
    }
    const int wid = tid >> 6;
    if ((tid & 63) == 0) { s_dl[wid] = sum_gt; s_ci[wid] = cnt_gt; }
    __syncthreads();
    if (tid == 0) {
        double sg = s_dl[0] + s_dl[1] + s_dl[2] + s_dl[3];
        int    cg = s_ci[0] + s_ci[1] + s_ci[2] + s_ci[3];
        double tk = 0.0;
        if (k > 0) tk = sg + (double)(k - cg) * (double)__uint_as_float(prefix);
        loss_c[b] = pos_ce[b] + tk;
    }
}

// ---------------- Kernel 4: final reduction ----------------
__global__ void final_kernel(const double* __restrict__ loss_l,
                             const double* __restrict__ loss_c,
                             const int*    __restrict__ num_pos,
                             float* __restrict__ out)
{
    int t = threadIdx.x; // 64 threads
    double ll = loss_l[t];
    double lc = loss_c[t];
    int    n  = num_pos[t];
    for (int off = 32; off; off >>= 1) {
        ll += __shfl_xor(ll, off);
        lc += __shfl_xor(lc, off);
        n  += __shfl_xor(n, off);
    }
    if (t == 0) {
        double N = (double)n;
        out[0] = (float)(ll / N);
        out[1] = (float)(lc / N);
    }
}

extern "C" void kernel_launch(void* const* d_in, const int* in_sizes, int n_in,
                              void* d_out, int out_size, void* d_ws, size_t ws_size,
                              hipStream_t stream)
{
    const float* loc_data  = (const float*)d_in[0];
    const float* conf_data = (const float*)d_in[1];
    const float* priors    = (const float*)d_in[2];
    const float* truths    = (const float*)d_in[3];
    const int*   labels    = (const int*)d_in[4];
    float* out = (float*)d_out;

    char* ws = (char*)d_ws;
    int* conf_t = (int*)ws;                                  // B*P ints, later reused as float loss_rank
    size_t off = (size_t)BATCH * P * sizeof(int);
    off = (off + 7) & ~(size_t)7;
    int* num_pos = (int*)(ws + off);     off += 64 * sizeof(int);
    off = (off + 7) & ~(size_t)7;
    double* loss_l = (double*)(ws + off); off += 64 * sizeof(double);
    double* pos_ce = (double*)(ws + off); off += 64 * sizeof(double);
    double* loss_c = (double*)(ws + off); off += 64 * sizeof(double);

    hipMemsetAsync(pos_ce, 0, 64 * sizeof(double), stream);

    match_kernel<<<BATCH, 256, 0, stream>>>(loc_data, priors, truths, labels,
                                            conf_t, num_pos, loss_l);
    ce_kernel<<<2048, 256, 0, stream>>>(conf_data, conf_t, pos_ce);
    topk_kernel<<<BATCH, 256, 0, stream>>>((const float*)conf_t, num_pos, pos_ce, loss_c);
    final_kernel<<<1, 64, 0, stream>>>(loss_l, loss_c, num_pos, out);
}